// Round 8
// baseline (1170.005 us; speedup 1.0000x reference)
//
#include <hip/hip_runtime.h>
#include <hip/hip_bf16.h>
#include <math.h>

// Problem constants (B=32, T=256, V=32000, D=512)
#define R   8192    // B*T rows
#define TT  256
#define D   512
#define V   32000
#define G3  1536    // 3*D (z|f|o)

typedef __attribute__((ext_vector_type(8))) short bf16x8;
typedef __attribute__((ext_vector_type(4))) float f32x4;
typedef __attribute__((ext_vector_type(4))) int   i32x4;
typedef __attribute__((ext_vector_type(8))) int   i32x8;

__device__ __forceinline__ float bf2f(ushort u) {
  union { unsigned int i; float f; } x; x.i = ((unsigned int)u) << 16; return x.f;
}
__device__ __forceinline__ ushort f2bf(float f) {   // RNE
  union { float f; unsigned int i; } x; x.f = f;
  unsigned int r = x.i + 0x7fffu + ((x.i >> 16) & 1u);
  return (ushort)(r >> 16);
}

// f32 -> OCP e4m3fn, round-nearest-even, clamp to 448. Exact integer-grid method.
__device__ __forceinline__ unsigned char f2e4m3(float f) {
  unsigned char s = (__float_as_uint(f) >> 31) ? 0x80 : 0x00;
  float a = fabsf(f);
  if (!(a < 448.f)) return s | 0x7e;       // clamp (no NaN/overflow in our data)
  if (a == 0.f) return s;
  int ef; frexpf(a, &ef);                  // a = m*2^ef, m in [0.5,1)
  int E = ef - 1;                          // a = (2m)*2^E
  if (E < -6) E = -6;                      // denormal grid
  float ulp = ldexpf(1.f, E - 3);
  int qi = (int)rintf(a / ulp);            // exact scale (pow2), RNE, qi in [0,16]
  if (qi >= 16) { E += 1; qi = 8; }
  unsigned char bits = (qi < 8) ? (unsigned char)qi
                                : (unsigned char)(((E + 7) << 3) | (qi - 8));
  return s | bits;
}

// phys-K transpose within each 128-elem block: element k stored at
// poff(k) = (k&~127) | h*32 | ks*8 | j  where k = (k&~127)+ks*32+h*8+j.
// Lane h's 4x8B K-slices (ks=0..3) land contiguous 32B -> the exact v8i32
// operand of the K=128 scaled MFMA.
__device__ __forceinline__ int physk(int d) {
  return (d & ~127) | (((d >> 3) & 3) << 5) | (((d >> 5) & 3) << 3) | (d & 7);
}

__device__ __forceinline__ void gload16(const void* g, void* l) {
  __builtin_amdgcn_global_load_lds((const __attribute__((address_space(1))) void*)g,
                                   (__attribute__((address_space(3))) void*)l, 16, 0, 0);
}

// ---------------- embedding gather -> XA bf16 [R][1024] = [x_prev | x] ----------------
__global__ __launch_bounds__(256) void embed_kernel(const int* __restrict__ tok,
                                                    const float4* __restrict__ emb,
                                                    ushort4* __restrict__ XA) {
  int idx = blockIdx.x * 256 + threadIdx.x;   // over R*128 float4s
  int r = idx >> 7, d4 = idx & 127;
  float4 v = emb[(size_t)tok[r] * 128 + d4];
  ushort4 h; h.x = f2bf(v.x); h.y = f2bf(v.y); h.z = f2bf(v.z); h.w = f2bf(v.w);
  XA[(size_t)r * 256 + 128 + d4] = h;                       // x part
  int t = r & (TT - 1);
  if (t < TT - 1) XA[(size_t)(r + 1) * 256 + d4] = h;       // next row's x_prev
  if (t == 0) { ushort4 z4; z4.x=z4.y=z4.z=z4.w=0; XA[(size_t)r * 256 + d4] = z4; }
}

// ---------------- weight transpose+convert: WcatT[1536][1024] bf16 ----------------
__global__ __launch_bounds__(256) void wconv(const float* __restrict__ Wz,
                                             const float* __restrict__ Wf,
                                             const float* __restrict__ Wo,
                                             ushort* __restrict__ WT) {
  __shared__ float tile[64][65];
  int z = blockIdx.z, g = z >> 1, i = z & 1;
  const float* src = (g == 0) ? Wz : (g == 1 ? Wf : Wo);
  src += (size_t)i * D * D;
  int d0 = blockIdx.x * 64, e0 = blockIdx.y * 64;
  int t = threadIdx.x, c = t & 63, rq = t >> 6;
#pragma unroll
  for (int p = 0; p < 16; ++p) {
    int dd = p * 4 + rq;
    tile[dd][c] = src[(size_t)(d0 + dd) * D + e0 + c];
  }
  __syncthreads();
#pragma unroll
  for (int p = 0; p < 16; ++p) {
    int ee = p * 4 + rq;
    WT[(size_t)(g * D + e0 + ee) * 1024 + i * D + d0 + c] = f2bf(tile[c][ee]);
  }
}

// ---------------- softmax weight transpose+convert: SW8T[32000][512] fp8 phys-K ----------------
__global__ __launch_bounds__(256) void swconv(const float* __restrict__ SW,
                                              unsigned char* __restrict__ SWT) {
  __shared__ float tile[64][65];
  int k0 = blockIdx.x * 64, n0 = blockIdx.y * 64;
  int t = threadIdx.x, c = t & 63, rq = t >> 6;
#pragma unroll
  for (int p = 0; p < 16; ++p) {
    int kk = p * 4 + rq;
    tile[kk][c] = SW[(size_t)(k0 + kk) * V + n0 + c];
  }
  __syncthreads();
  int poff = physk(k0 + c);
#pragma unroll
  for (int p = 0; p < 16; ++p) {
    int nn = p * 4 + rq;
    SWT[(size_t)(n0 + nn) * D + poff] = f2e4m3(tile[c][nn]);
  }
}

// ---------------- bias concat ----------------
__global__ void bcat_kernel(const float* bz0, const float* bf0, const float* bo0,
                            const float* bz1, const float* bf1, const float* bo1,
                            float* BC0, float* BC1) {
  int idx = blockIdx.x * 256 + threadIdx.x;
  if (idx >= 2 * G3) return;
  int layer = idx / G3, rem = idx % G3, g = rem >> 9, e = rem & 511;
  const float* s = (layer == 0) ? (g == 0 ? bz0 : (g == 1 ? bf0 : bo0))
                                : (g == 0 ? bz1 : (g == 1 ? bf1 : bo1));
  (layer == 0 ? BC0 : BC1)[rem] = s[e];
}

// ---------------- round-2 single-buffer bf16 MFMA core (for gemm_pre) ----------------
// C[128x128] per 256-thread block (4 waves, 2x2 of 64x64 wave tiles, 4x4 frags).
template<int KTOT, int LDA, int LDB>
__device__ __forceinline__ void gemm_tile_sb(const ushort* __restrict__ A,
                                             const ushort* __restrict__ B,
                                             int row0, int col0,
                                             char* As, char* Bs, f32x4 acc[4][4]) {
  const int t = threadIdx.x, lane = t & 63, w = t >> 6;
  const int wm = w >> 1, wn = w & 1;
  const int lrow = lane >> 3;
  const int slot = (lane & 7) ^ lrow;
  const int lo = lane & 15, hi = lane >> 4;

  const ushort* ga0 = A + (size_t)(row0 + w * 32 + lrow) * LDA + slot * 8;
  const ushort* gb0 = B + (size_t)(col0 + w * 32 + lrow) * LDB + slot * 8;

#pragma unroll 1
  for (int k0 = 0; k0 < KTOT; k0 += 64) {
#pragma unroll
    for (int i = 0; i < 4; ++i) {
      int chunk = w * 4 + i;
      gload16(ga0 + (size_t)i * 8 * LDA + k0, As + chunk * 1024);
      gload16(gb0 + (size_t)i * 8 * LDB + k0, Bs + chunk * 1024);
    }
    __syncthreads();
#pragma unroll
    for (int ks = 0; ks < 2; ++ks) {
      bf16x8 av[4], bv[4];
#pragma unroll
      for (int mi = 0; mi < 4; ++mi) {
        int row = wm * 64 + mi * 16 + lo;
        int sl  = (ks * 4 + hi) ^ (row & 7);
        av[mi] = *(const bf16x8*)(As + row * 128 + sl * 16);
      }
#pragma unroll
      for (int ni = 0; ni < 4; ++ni) {
        int row = wn * 64 + ni * 16 + lo;
        int sl  = (ks * 4 + hi) ^ (row & 7);
        bv[ni] = *(const bf16x8*)(Bs + row * 128 + sl * 16);
      }
#pragma unroll
      for (int mi = 0; mi < 4; ++mi)
#pragma unroll
        for (int ni = 0; ni < 4; ++ni)
          acc[mi][ni] = __builtin_amdgcn_mfma_f32_16x16x32_bf16(av[mi], bv[ni], acc[mi][ni], 0, 0, 0);
    }
    __syncthreads();
  }
}

// ---------------- QRNN pre-activation GEMM (8192x1536x1024, bf16) ----------------
__global__ __launch_bounds__(256) void gemm_pre(const ushort* __restrict__ A,
                                                const ushort* __restrict__ B,
                                                const float* __restrict__ bcat,
                                                ushort* __restrict__ PRE) {
  __shared__ char lds[32768];
  f32x4 acc[4][4];
#pragma unroll
  for (int i = 0; i < 4; ++i)
#pragma unroll
    for (int j = 0; j < 4; ++j) { f32x4 z = {0.f,0.f,0.f,0.f}; acc[i][j] = z; }
  const int row0 = blockIdx.x * 128, col0 = blockIdx.y * 128;
  gemm_tile_sb<1024,1024,1024>(A, B, row0, col0, lds, lds + 16384, acc);
  const int lane = threadIdx.x & 63, w = threadIdx.x >> 6;
  const int wm = w >> 1, wn = w & 1, lo = lane & 15, hi = lane >> 4;
#pragma unroll
  for (int ni = 0; ni < 4; ++ni) {
    int col = col0 + wn * 64 + ni * 16 + lo;
    float bb = bcat[col];
#pragma unroll
    for (int mi = 0; mi < 4; ++mi) {
      int r0 = row0 + wm * 64 + mi * 16 + hi * 4;
#pragma unroll
      for (int j = 0; j < 4; ++j)
        PRE[(size_t)(r0 + j) * G3 + col] = f2bf(acc[mi][ni][j] + bb);
    }
  }
}

// ---------------- MX-fp8 logits GEMM (8192x32000x512) + fused exp-sum + target ----------------
// v4: 256x256 block, 512 threads = 8 waves (wm 0..1 x wn 0..3), wave tile
// 128x64 (mi 0..7, ni 0..3). BK=128 (one scaled-MFMA K-block per kt, 4 kts).
// LDS = A 32KB + B 32KB single-buffered = 64KB -> 2 blocks/CU = 16 waves/CU.
// vs v3: LDS-read bytes per FLOP x0.75 (bigger wave tile), occupancy 2x.
// Row = 128B = 8 slots of 16B; LDS slot s of row r holds source slot s^(r&7)
// (pre-swizzled global source, rule #21); frag reads at slots (hi*2+q)^(lo&7).
__global__ __launch_bounds__(512, 4) void gemm_lse_fp8(const unsigned char* __restrict__ A,
                                                       const unsigned char* __restrict__ B,
                                                       const float* __restrict__ SB,
                                                       const int* __restrict__ tgt,
                                                       float* __restrict__ SUM,
                                                       float* __restrict__ TGL) {
  __shared__ char lds[65536];
  char* As = lds;
  char* Bs = lds + 32768;
  const int t = threadIdx.x, lane = t & 63, w = t >> 6;
  const int wm = w >> 2, wn = w & 3;
  const int lo = lane & 15, hi = lane >> 4;
  const int row0 = blockIdx.x * 256, col0 = blockIdx.y * 256;

  f32x4 acc[8][4];
#pragma unroll
  for (int i = 0; i < 8; ++i)
#pragma unroll
    for (int j = 0; j < 4; ++j) { f32x4 z = {0.f,0.f,0.f,0.f}; acc[i][j] = z; }

  // staging geometry: each issue covers 64 rows x 128B = 8KB (512 thr x 16B)
  const int gr = t >> 3;             // row within issue (0..63)
  const int ss = (t & 7) ^ (gr & 7); // inverse-swizzled source slot
  const int x  = lo & 7;             // frag-read row swizzle

#pragma unroll 1
  for (int kt = 0; kt < 4; ++kt) {
    const int k0 = kt * 128;         // byte == element offset (fp8 phys-K)
#pragma unroll
    for (int i = 0; i < 4; ++i) {
      gload16(A + (size_t)(row0 + i * 64 + gr) * 512 + k0 + ss * 16,
              As + i * 8192 + t * 16);
      gload16(B + (size_t)(col0 + i * 64 + gr) * 512 + k0 + ss * 16,
              Bs + i * 8192 + t * 16);
    }
    __syncthreads();
    // ---- compute: one scaled K=128 MFMA per (mi,ni) ----
    i32x8 b8[4];
#pragma unroll
    for (int ni = 0; ni < 4; ++ni) {
      const char* rb = Bs + (wn * 64 + ni * 16 + lo) * 128;
      union { i32x8 v8; i32x4 v4[2]; } u;
      u.v4[0] = *(const i32x4*)(rb + ((hi * 2 + 0) ^ x) * 16);
      u.v4[1] = *(const i32x4*)(rb + ((hi * 2 + 1) ^ x) * 16);
      b8[ni] = u.v8;
    }
#pragma unroll
    for (int mi = 0; mi < 8; ++mi) {
      const char* rb = As + (wm * 128 + mi * 16 + lo) * 128;
      union { i32x8 v8; i32x4 v4[2]; } u;
      u.v4[0] = *(const i32x4*)(rb + ((hi * 2 + 0) ^ x) * 16);
      u.v4[1] = *(const i32x4*)(rb + ((hi * 2 + 1) ^ x) * 16);
      i32x8 a8 = u.v8;
#pragma unroll
      for (int ni = 0; ni < 4; ++ni)
        acc[mi][ni] = __builtin_amdgcn_mfma_scale_f32_16x16x128_f8f6f4(
            a8, b8[ni], acc[mi][ni], 0, 0, 0, 0x7F, 0, 0x7F);
    }
    __syncthreads();
  }

  // epilogue: bias, exp, per-row partial sums; capture target logit
#pragma unroll
  for (int mi = 0; mi < 8; ++mi) {
    int r0 = row0 + wm * 128 + mi * 16 + hi * 4;
    int tg[4];
    float s[4] = {0.f, 0.f, 0.f, 0.f};
#pragma unroll
    for (int j = 0; j < 4; ++j) tg[j] = tgt[r0 + j];
#pragma unroll
    for (int ni = 0; ni < 4; ++ni) {
      int col = col0 + wn * 64 + ni * 16 + lo;
      float bb = SB[col];
#pragma unroll
      for (int j = 0; j < 4; ++j) {
        float v = acc[mi][ni][j] + bb;
        if (col == tg[j]) TGL[r0 + j] = v;   // exactly one writer per row
        s[j] += __expf(v);
      }
    }
#pragma unroll
    for (int m = 1; m < 16; m <<= 1) {
#pragma unroll
      for (int j = 0; j < 4; ++j) s[j] += __shfl_xor(s[j], m, 64);
    }
    if (lo == 0) {
#pragma unroll
      for (int j = 0; j < 4; ++j) atomicAdd(&SUM[r0 + j], s[j]);
    }
  }
}

// ---------------- fo-pool scan (bf16 in; bf16 out mode 0, phys-K fp8 out mode 1) ----------------
__global__ __launch_bounds__(64) void scan_kernel(const ushort* __restrict__ PRE,
                                                  ushort* __restrict__ OUT16,
                                                  unsigned char* __restrict__ OUT8,
                                                  int mode) {
  int idx = blockIdx.x * 64 + threadIdx.x;    // 32*512
  int b = idx >> 9, d = idx & 511;
  const ushort* p = PRE + (size_t)b * TT * G3 + d;
  int poff = physk(d);
  float c = 0.f;
  for (int t0 = 0; t0 < TT; t0 += 8) {
    float pz[8], pf[8], po[8];
#pragma unroll
    for (int i = 0; i < 8; ++i) {
      const ushort* q = p + (size_t)(t0 + i) * G3;
      pz[i] = bf2f(q[0]); pf[i] = bf2f(q[512]); po[i] = bf2f(q[1024]);
    }
#pragma unroll
    for (int i = 0; i < 8; ++i) {
      float z = 2.f / (1.f + __expf(-2.f * pz[i])) - 1.f;
      float f = 1.f / (1.f + __expf(-pf[i]));
      float o = 1.f / (1.f + __expf(-po[i]));
      c = f * c + (1.f - f) * z;
      float h = o * c;
      int tt = t0 + i;
      size_t r = (size_t)b * TT + tt;
      if (mode == 0) {
        ushort hb = f2bf(h);
        OUT16[r * 1024 + 512 + d] = hb;
        if (tt < TT - 1) OUT16[(r + 1) * 1024 + d] = hb;
        if (tt == 0)     OUT16[r * 1024 + d] = 0;
      } else {
        OUT8[r * 512 + poff] = f2e4m3(h);
      }
    }
  }
}

// ---------------- helpers ----------------
__global__ void zero_kernel(float* __restrict__ p, int n) {
  int i = blockIdx.x * 256 + threadIdx.x;
  if (i < n) p[i] = 0.f;
}

__global__ __launch_bounds__(256) void cost_kernel(const float* __restrict__ sumexp,
                                                   const float* __restrict__ tgl,
                                                   float* __restrict__ out) {
  int t = threadIdx.x;
  float s = 0.f;
  for (int r = t; r < R; r += 256) s += logf(sumexp[r]) - tgl[r];
#pragma unroll
  for (int m = 1; m < 64; m <<= 1) s += __shfl_xor(s, m, 64);
  __shared__ float red[4];
  int wave = t >> 6, lane = t & 63;
  if (lane == 0) red[wave] = s;
  __syncthreads();
  if (t == 0) out[0] = (red[0] + red[1] + red[2] + red[3]) / (float)R;
}

extern "C" void kernel_launch(void* const* d_in, const int* in_sizes, int n_in,
                              void* d_out, int out_size, void* d_ws, size_t ws_size,
                              hipStream_t stream) {
  const int*   tok = (const int*)d_in[0];
  const int*   tgt = (const int*)d_in[1];
  const float* emb = (const float*)d_in[2];
  const float* Wz0 = (const float*)d_in[3];  const float* bz0 = (const float*)d_in[4];
  const float* Wf0 = (const float*)d_in[5];  const float* bf0 = (const float*)d_in[6];
  const float* Wo0 = (const float*)d_in[7];  const float* bo0 = (const float*)d_in[8];
  const float* Wz1 = (const float*)d_in[9];  const float* bz1 = (const float*)d_in[10];
  const float* Wf1 = (const float*)d_in[11]; const float* bf1 = (const float*)d_in[12];
  const float* Wo1 = (const float*)d_in[13]; const float* bo1 = (const float*)d_in[14];
  const float* SW  = (const float*)d_in[15]; const float* SB  = (const float*)d_in[16];
  float* out = (float*)d_out;

  // workspace layout (bytes):
  char* base = (char*)d_ws;
  ushort*        XA  = (ushort*)(base);               // 16,777,216  [R][1024] bf16
  ushort*        YA  = (ushort*)(base + 16777216);    // 16,777,216  [R][1024] bf16
  ushort*        PRE = (ushort*)(base + 33554432);    // 25,165,824  [R][1536] bf16
  unsigned char* H8  = (unsigned char*)(base + 58720256);  // 4,194,304 [R][512] fp8 phys-K
  ushort*        WT0 = (ushort*)(base + 67108864);    //  3,145,728  [1536][1024] bf16
  ushort*        WT1 = (ushort*)(base + 70254592);    //  3,145,728
  float*         BC0 = (float*)(base + 73400320);     //  6,144
  float*         BC1 = (float*)(base + 73406464);     //  6,144
  float*         SUM = (float*)(base + 73412608);     //  32,768
  float*         TGL = (float*)(base + 73445376);     //  32,768
  unsigned char* SW8T = (unsigned char*)(base);       // 16,384,000 — aliases XA (dead by then)

  embed_kernel<<<R * 128 / 256, 256, 0, stream>>>(tok, (const float4*)emb, (ushort4*)XA);
  wconv<<<dim3(8, 8, 6), 256, 0, stream>>>(Wz0, Wf0, Wo0, WT0);
  wconv<<<dim3(8, 8, 6), 256, 0, stream>>>(Wz1, Wf1, Wo1, WT1);
  bcat_kernel<<<12, 256, 0, stream>>>(bz0, bf0, bo0, bz1, bf1, bo1, BC0, BC1);

  gemm_pre<<<dim3(64, 12), 256, 0, stream>>>(XA, WT0, BC0, PRE);
  scan_kernel<<<256, 64, 0, stream>>>(PRE, YA, nullptr, 0);
  gemm_pre<<<dim3(64, 12), 256, 0, stream>>>(YA, WT1, BC1, PRE);
  scan_kernel<<<256, 64, 0, stream>>>(PRE, nullptr, H8, 1);

  // SW8T aliases XA — dead after the first gemm_pre
  swconv<<<dim3(8, 500), 256, 0, stream>>>(SW, SW8T);
  zero_kernel<<<32, 256, 0, stream>>>(SUM, R);
  gemm_lse_fp8<<<dim3(32, 125), 512, 0, stream>>>(H8, SW8T, SB, tgt, SUM, TGL);
  cost_kernel<<<1, 256, 0, stream>>>(SUM, TGL, out);
}

// Round 9
// 465.613 us; speedup vs baseline: 2.5128x; 2.5128x over previous
//
#include <hip/hip_runtime.h>
#include <hip/hip_bf16.h>
#include <math.h>

// Problem constants (B=32, T=256, V=32000, D=512)
#define R   8192    // B*T rows
#define TT  256
#define D   512
#define V   32000
#define G3  1536    // 3*D (z|f|o)

typedef __attribute__((ext_vector_type(8))) short bf16x8;
typedef __attribute__((ext_vector_type(4))) float f32x4;
typedef __attribute__((ext_vector_type(4))) int   i32x4;
typedef __attribute__((ext_vector_type(8))) int   i32x8;

__device__ __forceinline__ float bf2f(ushort u) {
  union { unsigned int i; float f; } x; x.i = ((unsigned int)u) << 16; return x.f;
}
__device__ __forceinline__ ushort f2bf(float f) {   // RNE
  union { float f; unsigned int i; } x; x.f = f;
  unsigned int r = x.i + 0x7fffu + ((x.i >> 16) & 1u);
  return (ushort)(r >> 16);
}

// f32 -> OCP e4m3fn, round-nearest-even, clamp to 448. Exact integer-grid method.
__device__ __forceinline__ unsigned char f2e4m3(float f) {
  unsigned char s = (__float_as_uint(f) >> 31) ? 0x80 : 0x00;
  float a = fabsf(f);
  if (!(a < 448.f)) return s | 0x7e;       // clamp (no NaN/overflow in our data)
  if (a == 0.f) return s;
  int ef; frexpf(a, &ef);                  // a = m*2^ef, m in [0.5,1)
  int E = ef - 1;                          // a = (2m)*2^E
  if (E < -6) E = -6;                      // denormal grid
  float ulp = ldexpf(1.f, E - 3);
  int qi = (int)rintf(a / ulp);            // exact scale (pow2), RNE, qi in [0,16]
  if (qi >= 16) { E += 1; qi = 8; }
  unsigned char bits = (qi < 8) ? (unsigned char)qi
                                : (unsigned char)(((E + 7) << 3) | (qi - 8));
  return s | bits;
}

// phys-K transpose within each 128-elem block: element k stored at
// poff(k) = (k&~127) | h*32 | ks*8 | j  where k = (k&~127)+ks*32+h*8+j.
// Lane h's 4x8B K-slices (ks=0..3) land contiguous 32B -> the exact v8i32
// operand of the K=128 scaled MFMA.
__device__ __forceinline__ int physk(int d) {
  return (d & ~127) | (((d >> 3) & 3) << 5) | (((d >> 5) & 3) << 3) | (d & 7);
}

__device__ __forceinline__ void gload16(const void* g, void* l) {
  __builtin_amdgcn_global_load_lds((const __attribute__((address_space(1))) void*)g,
                                   (__attribute__((address_space(3))) void*)l, 16, 0, 0);
}

// ---------------- embedding gather -> XA bf16 [R][1024] = [x_prev | x] ----------------
__global__ __launch_bounds__(256) void embed_kernel(const int* __restrict__ tok,
                                                    const float4* __restrict__ emb,
                                                    ushort4* __restrict__ XA) {
  int idx = blockIdx.x * 256 + threadIdx.x;   // over R*128 float4s
  int r = idx >> 7, d4 = idx & 127;
  float4 v = emb[(size_t)tok[r] * 128 + d4];
  ushort4 h; h.x = f2bf(v.x); h.y = f2bf(v.y); h.z = f2bf(v.z); h.w = f2bf(v.w);
  XA[(size_t)r * 256 + 128 + d4] = h;                       // x part
  int t = r & (TT - 1);
  if (t < TT - 1) XA[(size_t)(r + 1) * 256 + d4] = h;       // next row's x_prev
  if (t == 0) { ushort4 z4; z4.x=z4.y=z4.z=z4.w=0; XA[(size_t)r * 256 + d4] = z4; }
}

// ---------------- weight transpose+convert: WcatT[1536][1024] bf16 ----------------
__global__ __launch_bounds__(256) void wconv(const float* __restrict__ Wz,
                                             const float* __restrict__ Wf,
                                             const float* __restrict__ Wo,
                                             ushort* __restrict__ WT) {
  __shared__ float tile[64][65];
  int z = blockIdx.z, g = z >> 1, i = z & 1;
  const float* src = (g == 0) ? Wz : (g == 1 ? Wf : Wo);
  src += (size_t)i * D * D;
  int d0 = blockIdx.x * 64, e0 = blockIdx.y * 64;
  int t = threadIdx.x, c = t & 63, rq = t >> 6;
#pragma unroll
  for (int p = 0; p < 16; ++p) {
    int dd = p * 4 + rq;
    tile[dd][c] = src[(size_t)(d0 + dd) * D + e0 + c];
  }
  __syncthreads();
#pragma unroll
  for (int p = 0; p < 16; ++p) {
    int ee = p * 4 + rq;
    WT[(size_t)(g * D + e0 + ee) * 1024 + i * D + d0 + c] = f2bf(tile[c][ee]);
  }
}

// ---------------- softmax weight transpose+convert: SW8T[32000][512] fp8 phys-K ----------------
__global__ __launch_bounds__(256) void swconv(const float* __restrict__ SW,
                                              unsigned char* __restrict__ SWT) {
  __shared__ float tile[64][65];
  int k0 = blockIdx.x * 64, n0 = blockIdx.y * 64;
  int t = threadIdx.x, c = t & 63, rq = t >> 6;
#pragma unroll
  for (int p = 0; p < 16; ++p) {
    int kk = p * 4 + rq;
    tile[kk][c] = SW[(size_t)(k0 + kk) * V + n0 + c];
  }
  __syncthreads();
  int poff = physk(k0 + c);
#pragma unroll
  for (int p = 0; p < 16; ++p) {
    int nn = p * 4 + rq;
    SWT[(size_t)(n0 + nn) * D + poff] = f2e4m3(tile[c][nn]);
  }
}

// ---------------- bias concat ----------------
__global__ void bcat_kernel(const float* bz0, const float* bf0, const float* bo0,
                            const float* bz1, const float* bf1, const float* bo1,
                            float* BC0, float* BC1) {
  int idx = blockIdx.x * 256 + threadIdx.x;
  if (idx >= 2 * G3) return;
  int layer = idx / G3, rem = idx % G3, g = rem >> 9, e = rem & 511;
  const float* s = (layer == 0) ? (g == 0 ? bz0 : (g == 1 ? bf0 : bo0))
                                : (g == 0 ? bz1 : (g == 1 ? bf1 : bo1));
  (layer == 0 ? BC0 : BC1)[rem] = s[e];
}

// ---------------- round-2 single-buffer bf16 MFMA core (for gemm_pre) ----------------
// C[128x128] per 256-thread block (4 waves, 2x2 of 64x64 wave tiles, 4x4 frags).
template<int KTOT, int LDA, int LDB>
__device__ __forceinline__ void gemm_tile_sb(const ushort* __restrict__ A,
                                             const ushort* __restrict__ B,
                                             int row0, int col0,
                                             char* As, char* Bs, f32x4 acc[4][4]) {
  const int t = threadIdx.x, lane = t & 63, w = t >> 6;
  const int wm = w >> 1, wn = w & 1;
  const int lrow = lane >> 3;
  const int slot = (lane & 7) ^ lrow;
  const int lo = lane & 15, hi = lane >> 4;

  const ushort* ga0 = A + (size_t)(row0 + w * 32 + lrow) * LDA + slot * 8;
  const ushort* gb0 = B + (size_t)(col0 + w * 32 + lrow) * LDB + slot * 8;

#pragma unroll 1
  for (int k0 = 0; k0 < KTOT; k0 += 64) {
#pragma unroll
    for (int i = 0; i < 4; ++i) {
      int chunk = w * 4 + i;
      gload16(ga0 + (size_t)i * 8 * LDA + k0, As + chunk * 1024);
      gload16(gb0 + (size_t)i * 8 * LDB + k0, Bs + chunk * 1024);
    }
    __syncthreads();
#pragma unroll
    for (int ks = 0; ks < 2; ++ks) {
      bf16x8 av[4], bv[4];
#pragma unroll
      for (int mi = 0; mi < 4; ++mi) {
        int row = wm * 64 + mi * 16 + lo;
        int sl  = (ks * 4 + hi) ^ (row & 7);
        av[mi] = *(const bf16x8*)(As + row * 128 + sl * 16);
      }
#pragma unroll
      for (int ni = 0; ni < 4; ++ni) {
        int row = wn * 64 + ni * 16 + lo;
        int sl  = (ks * 4 + hi) ^ (row & 7);
        bv[ni] = *(const bf16x8*)(Bs + row * 128 + sl * 16);
      }
#pragma unroll
      for (int mi = 0; mi < 4; ++mi)
#pragma unroll
        for (int ni = 0; ni < 4; ++ni)
          acc[mi][ni] = __builtin_amdgcn_mfma_f32_16x16x32_bf16(av[mi], bv[ni], acc[mi][ni], 0, 0, 0);
    }
    __syncthreads();
  }
}

// ---------------- QRNN pre-activation GEMM (8192x1536x1024, bf16) ----------------
__global__ __launch_bounds__(256) void gemm_pre(const ushort* __restrict__ A,
                                                const ushort* __restrict__ B,
                                                const float* __restrict__ bcat,
                                                ushort* __restrict__ PRE) {
  __shared__ char lds[32768];
  f32x4 acc[4][4];
#pragma unroll
  for (int i = 0; i < 4; ++i)
#pragma unroll
    for (int j = 0; j < 4; ++j) { f32x4 z = {0.f,0.f,0.f,0.f}; acc[i][j] = z; }
  const int row0 = blockIdx.x * 128, col0 = blockIdx.y * 128;
  gemm_tile_sb<1024,1024,1024>(A, B, row0, col0, lds, lds + 16384, acc);
  const int lane = threadIdx.x & 63, w = threadIdx.x >> 6;
  const int wm = w >> 1, wn = w & 1, lo = lane & 15, hi = lane >> 4;
#pragma unroll
  for (int ni = 0; ni < 4; ++ni) {
    int col = col0 + wn * 64 + ni * 16 + lo;
    float bb = bcat[col];
#pragma unroll
    for (int mi = 0; mi < 4; ++mi) {
      int r0 = row0 + wm * 64 + mi * 16 + hi * 4;
#pragma unroll
      for (int j = 0; j < 4; ++j)
        PRE[(size_t)(r0 + j) * G3 + col] = f2bf(acc[mi][ni][j] + bb);
    }
  }
}

// ---------------- MX-fp8 logits GEMM (8192x32000x512) + fused exp-sum + target ----------------
// v5: 128x128 tile (proven v3 core) with two fixes:
//  - BK=128 -> 32KB LDS -> 4 blocks/CU (16 waves/CU, 2x v3 occupancy).
//  - SWAPPED MFMA operands: acc[mi][ni] = mfma(b8[ni], a8[mi]) puts the OUTPUT
//    ROW on lane&15 and the VOCAB COL on (lane>>4)*4+j -> each lane accumulates
//    its row's exp-sum in-register over (ni,j); only a 2-stage hi-lane shfl
//    remains (8 shfl/wave vs 256 bpermute in v3).
// Row = 128B = 8 slots of 16B; LDS slot s of row r holds source slot s^(r&7)
// (pre-swizzled global source, rule #21); frag reads at slots (hi*2+q)^(r&7).
__global__ __launch_bounds__(256, 2) void gemm_lse_fp8(const unsigned char* __restrict__ A,
                                                       const unsigned char* __restrict__ B,
                                                       const float* __restrict__ SB,
                                                       const int* __restrict__ tgt,
                                                       float* __restrict__ SUM,
                                                       float* __restrict__ TGL) {
  __shared__ char lds[32768];
  char* As = lds;
  char* Bs = lds + 16384;
  const int t = threadIdx.x, lane = t & 63, w = t >> 6;
  const int wm = w >> 1, wn = w & 1;
  const int lo = lane & 15, hi = lane >> 4;
  const int row0 = blockIdx.x * 128, col0 = blockIdx.y * 128;

  f32x4 acc[4][4];
#pragma unroll
  for (int i = 0; i < 4; ++i)
#pragma unroll
    for (int j = 0; j < 4; ++j) { f32x4 z = {0.f,0.f,0.f,0.f}; acc[i][j] = z; }

  // staging geometry: each issue covers 32 rows x 128B = 4KB (256 thr x 16B)
  const int gr = t >> 3;             // row within issue (0..31)
  const int ss = (t & 7) ^ (gr & 7); // inverse-swizzled source slot
  const int x  = lo & 7;             // frag-read row swizzle

#pragma unroll 1
  for (int kt = 0; kt < 4; ++kt) {
    const int k0 = kt * 128;         // byte == element offset (fp8 phys-K)
#pragma unroll
    for (int i = 0; i < 4; ++i) {
      gload16(A + (size_t)(row0 + i * 32 + gr) * 512 + k0 + ss * 16,
              As + i * 4096 + t * 16);
      gload16(B + (size_t)(col0 + i * 32 + gr) * 512 + k0 + ss * 16,
              Bs + i * 4096 + t * 16);
    }
    __syncthreads();
    // ---- compute: one scaled K=128 MFMA per (mi,ni), operands SWAPPED ----
    i32x8 b8[4];
#pragma unroll
    for (int ni = 0; ni < 4; ++ni) {
      const char* rb = Bs + (wn * 64 + ni * 16 + lo) * 128;
      union { i32x8 v8; i32x4 v4[2]; } u;
      u.v4[0] = *(const i32x4*)(rb + ((hi * 2 + 0) ^ x) * 16);
      u.v4[1] = *(const i32x4*)(rb + ((hi * 2 + 1) ^ x) * 16);
      b8[ni] = u.v8;
    }
#pragma unroll
    for (int mi = 0; mi < 4; ++mi) {
      const char* rb = As + (wm * 64 + mi * 16 + lo) * 128;
      union { i32x8 v8; i32x4 v4[2]; } u;
      u.v4[0] = *(const i32x4*)(rb + ((hi * 2 + 0) ^ x) * 16);
      u.v4[1] = *(const i32x4*)(rb + ((hi * 2 + 1) ^ x) * 16);
      i32x8 a8 = u.v8;
#pragma unroll
      for (int ni = 0; ni < 4; ++ni)
        acc[mi][ni] = __builtin_amdgcn_mfma_scale_f32_16x16x128_f8f6f4(
            b8[ni], a8, acc[mi][ni], 0, 0, 0, 0x7F, 0, 0x7F);
    }
    __syncthreads();
  }

  // epilogue (swapped layout): out_row = row0+wm*64+mi*16+lo (lane-local!),
  // vocab_col = col0+wn*64+ni*16+hi*4+j. In-lane exp-sum over (ni,j);
  // 2-stage shfl over hi lanes; one atomic per row per wave.
#pragma unroll
  for (int mi = 0; mi < 4; ++mi) {
    const int row = row0 + wm * 64 + mi * 16 + lo;
    const int tg  = tgt[row];
    float s = 0.f;
#pragma unroll
    for (int ni = 0; ni < 4; ++ni) {
      const int colb = col0 + wn * 64 + ni * 16 + hi * 4;
#pragma unroll
      for (int j = 0; j < 4; ++j) {
        float v = acc[mi][ni][j] + SB[colb + j];
        if (colb + j == tg) TGL[row] = v;    // exactly one writer per row
        s += __expf(v);
      }
    }
    s += __shfl_xor(s, 16, 64);
    s += __shfl_xor(s, 32, 64);
    if (hi == 0) atomicAdd(&SUM[row], s);
  }
}

// ---------------- fo-pool scan (bf16 in; bf16 out mode 0, phys-K fp8 out mode 1) ----------------
__global__ __launch_bounds__(64) void scan_kernel(const ushort* __restrict__ PRE,
                                                  ushort* __restrict__ OUT16,
                                                  unsigned char* __restrict__ OUT8,
                                                  int mode) {
  int idx = blockIdx.x * 64 + threadIdx.x;    // 32*512
  int b = idx >> 9, d = idx & 511;
  const ushort* p = PRE + (size_t)b * TT * G3 + d;
  int poff = physk(d);
  float c = 0.f;
  for (int t0 = 0; t0 < TT; t0 += 8) {
    float pz[8], pf[8], po[8];
#pragma unroll
    for (int i = 0; i < 8; ++i) {
      const ushort* q = p + (size_t)(t0 + i) * G3;
      pz[i] = bf2f(q[0]); pf[i] = bf2f(q[512]); po[i] = bf2f(q[1024]);
    }
#pragma unroll
    for (int i = 0; i < 8; ++i) {
      float z = 2.f / (1.f + __expf(-2.f * pz[i])) - 1.f;
      float f = 1.f / (1.f + __expf(-pf[i]));
      float o = 1.f / (1.f + __expf(-po[i]));
      c = f * c + (1.f - f) * z;
      float h = o * c;
      int tt = t0 + i;
      size_t r = (size_t)b * TT + tt;
      if (mode == 0) {
        ushort hb = f2bf(h);
        OUT16[r * 1024 + 512 + d] = hb;
        if (tt < TT - 1) OUT16[(r + 1) * 1024 + d] = hb;
        if (tt == 0)     OUT16[r * 1024 + d] = 0;
      } else {
        OUT8[r * 512 + poff] = f2e4m3(h);
      }
    }
  }
}

// ---------------- helpers ----------------
__global__ void zero_kernel(float* __restrict__ p, int n) {
  int i = blockIdx.x * 256 + threadIdx.x;
  if (i < n) p[i] = 0.f;
}

__global__ __launch_bounds__(256) void cost_kernel(const float* __restrict__ sumexp,
                                                   const float* __restrict__ tgl,
                                                   float* __restrict__ out) {
  int t = threadIdx.x;
  float s = 0.f;
  for (int r = t; r < R; r += 256) s += logf(sumexp[r]) - tgl[r];
#pragma unroll
  for (int m = 1; m < 64; m <<= 1) s += __shfl_xor(s, m, 64);
  __shared__ float red[4];
  int wave = t >> 6, lane = t & 63;
  if (lane == 0) red[wave] = s;
  __syncthreads();
  if (t == 0) out[0] = (red[0] + red[1] + red[2] + red[3]) / (float)R;
}

extern "C" void kernel_launch(void* const* d_in, const int* in_sizes, int n_in,
                              void* d_out, int out_size, void* d_ws, size_t ws_size,
                              hipStream_t stream) {
  const int*   tok = (const int*)d_in[0];
  const int*   tgt = (const int*)d_in[1];
  const float* emb = (const float*)d_in[2];
  const float* Wz0 = (const float*)d_in[3];  const float* bz0 = (const float*)d_in[4];
  const float* Wf0 = (const float*)d_in[5];  const float* bf0 = (const float*)d_in[6];
  const float* Wo0 = (const float*)d_in[7];  const float* bo0 = (const float*)d_in[8];
  const float* Wz1 = (const float*)d_in[9];  const float* bz1 = (const float*)d_in[10];
  const float* Wf1 = (const float*)d_in[11]; const float* bf1 = (const float*)d_in[12];
  const float* Wo1 = (const float*)d_in[13]; const float* bo1 = (const float*)d_in[14];
  const float* SW  = (const float*)d_in[15]; const float* SB  = (const float*)d_in[16];
  float* out = (float*)d_out;

  // workspace layout (bytes):
  char* base = (char*)d_ws;
  ushort*        XA  = (ushort*)(base);               // 16,777,216  [R][1024] bf16
  ushort*        YA  = (ushort*)(base + 16777216);    // 16,777,216  [R][1024] bf16
  ushort*        PRE = (ushort*)(base + 33554432);    // 25,165,824  [R][1536] bf16
  unsigned char* H8  = (unsigned char*)(base + 58720256);  // 4,194,304 [R][512] fp8 phys-K
  ushort*        WT0 = (ushort*)(base + 67108864);    //  3,145,728  [1536][1024] bf16
  ushort*        WT1 = (ushort*)(base + 70254592);    //  3,145,728
  float*         BC0 = (float*)(base + 73400320);     //  6,144
  float*         BC1 = (float*)(base + 73406464);     //  6,144
  float*         SUM = (float*)(base + 73412608);     //  32,768
  float*         TGL = (float*)(base + 73445376);     //  32,768
  unsigned char* SW8T = (unsigned char*)(base);       // 16,384,000 — aliases XA (dead by then)

  embed_kernel<<<R * 128 / 256, 256, 0, stream>>>(tok, (const float4*)emb, (ushort4*)XA);
  wconv<<<dim3(8, 8, 6), 256, 0, stream>>>(Wz0, Wf0, Wo0, WT0);
  wconv<<<dim3(8, 8, 6), 256, 0, stream>>>(Wz1, Wf1, Wo1, WT1);
  bcat_kernel<<<12, 256, 0, stream>>>(bz0, bf0, bo0, bz1, bf1, bo1, BC0, BC1);

  gemm_pre<<<dim3(64, 12), 256, 0, stream>>>(XA, WT0, BC0, PRE);
  scan_kernel<<<256, 64, 0, stream>>>(PRE, YA, nullptr, 0);
  gemm_pre<<<dim3(64, 12), 256, 0, stream>>>(YA, WT1, BC1, PRE);
  scan_kernel<<<256, 64, 0, stream>>>(PRE, nullptr, H8, 1);

  // SW8T aliases XA — dead after the first gemm_pre
  swconv<<<dim3(8, 500), 256, 0, stream>>>(SW, SW8T);
  zero_kernel<<<32, 256, 0, stream>>>(SUM, R);
  gemm_lse_fp8<<<dim3(64, 250), 256, 0, stream>>>(H8, SW8T, SB, tgt, SUM, TGL);
  cost_kernel<<<1, 256, 0, stream>>>(SUM, TGL, out);
}

// Round 10
// 458.924 us; speedup vs baseline: 2.5495x; 1.0146x over previous
//
#include <hip/hip_runtime.h>
#include <hip/hip_bf16.h>
#include <math.h>

// Problem constants (B=32, T=256, V=32000, D=512)
#define R   8192    // B*T rows
#define TT  256
#define D   512
#define V   32000
#define G3  1536    // 3*D (z|f|o)

typedef __attribute__((ext_vector_type(8))) short bf16x8;
typedef __attribute__((ext_vector_type(4))) float f32x4;
typedef __attribute__((ext_vector_type(4))) int   i32x4;
typedef __attribute__((ext_vector_type(8))) int   i32x8;

__device__ __forceinline__ float bf2f(ushort u) {
  union { unsigned int i; float f; } x; x.i = ((unsigned int)u) << 16; return x.f;
}
__device__ __forceinline__ ushort f2bf(float f) {   // RNE
  union { float f; unsigned int i; } x; x.f = f;
  unsigned int r = x.i + 0x7fffu + ((x.i >> 16) & 1u);
  return (ushort)(r >> 16);
}

// f32 -> OCP e4m3fn, round-nearest-even, clamp to 448. Exact integer-grid method.
__device__ __forceinline__ unsigned char f2e4m3(float f) {
  unsigned char s = (__float_as_uint(f) >> 31) ? 0x80 : 0x00;
  float a = fabsf(f);
  if (!(a < 448.f)) return s | 0x7e;       // clamp (no NaN/overflow in our data)
  if (a == 0.f) return s;
  int ef; frexpf(a, &ef);                  // a = m*2^ef, m in [0.5,1)
  int E = ef - 1;                          // a = (2m)*2^E
  if (E < -6) E = -6;                      // denormal grid
  float ulp = ldexpf(1.f, E - 3);
  int qi = (int)rintf(a / ulp);            // exact scale (pow2), RNE, qi in [0,16]
  if (qi >= 16) { E += 1; qi = 8; }
  unsigned char bits = (qi < 8) ? (unsigned char)qi
                                : (unsigned char)(((E + 7) << 3) | (qi - 8));
  return s | bits;
}

// phys-K transpose within each 128-elem block: element k stored at
// poff(k) = (k&~127) | h*32 | ks*8 | j  where k = (k&~127)+ks*32+h*8+j.
// Lane h's 4x8B K-slices (ks=0..3) land contiguous 32B -> the exact v8i32
// operand of the K=128 scaled MFMA.
__device__ __forceinline__ int physk(int d) {
  return (d & ~127) | (((d >> 3) & 3) << 5) | (((d >> 5) & 3) << 3) | (d & 7);
}

__device__ __forceinline__ void gload16(const void* g, void* l) {
  __builtin_amdgcn_global_load_lds((const __attribute__((address_space(1))) void*)g,
                                   (__attribute__((address_space(3))) void*)l, 16, 0, 0);
}

// ---------------- embedding gather -> XA8 fp8 phys-K [R][1024] = [x_prev | x] ----------------
__global__ __launch_bounds__(256) void embed_kernel(const int* __restrict__ tok,
                                                    const float4* __restrict__ emb,
                                                    unsigned char* __restrict__ XA8) {
  int idx = blockIdx.x * 256 + threadIdx.x;   // over R*128 float4s
  int r = idx >> 7, d4 = idx & 127;
  float4 v = emb[(size_t)tok[r] * 128 + d4];
  uchar4 h8;
  h8.x = f2e4m3(v.x); h8.y = f2e4m3(v.y); h8.z = f2e4m3(v.z); h8.w = f2e4m3(v.w);
  int pp = physk(d4 * 4);                     // aligned-4 contiguous run
  *(uchar4*)(XA8 + (size_t)r * 1024 + 512 + pp) = h8;          // x part
  int t = r & (TT - 1);
  if (t < TT - 1) *(uchar4*)(XA8 + (size_t)(r + 1) * 1024 + pp) = h8;  // next row x_prev
  if (t == 0) { uchar4 z = {0, 0, 0, 0}; *(uchar4*)(XA8 + (size_t)r * 1024 + pp) = z; }
}

// ---------------- coalesced fp8 phys-K transpose-convert helper ----------------
// tile[64][65] holds [k][n] f32 for k in [k0,k0+64), n in [n0,n0+64).
// phys-K image of this 64-k half-block within each output row = 4 runs of 16B
// at (k0&~127) + h*32 + ((k0&64)?16:0), byte ksl*8+j <- element ksl*32+h*8+j.
// 256 threads: (nn = t&63, h = t>>6) each emit one 16B store.
__device__ __forceinline__ void tconv_write(const float (*tile)[65],
                                            unsigned char* __restrict__ dstrow0,
                                            size_t ldb, int k0, int t) {
  int nn = t & 63, h = t >> 6;
  union { unsigned char c[16]; uint4 q; } u;
#pragma unroll
  for (int ksl = 0; ksl < 2; ++ksl)
#pragma unroll
    for (int j = 0; j < 8; ++j)
      u.c[ksl * 8 + j] = f2e4m3(tile[ksl * 32 + h * 8 + j][nn]);
  unsigned char* dst = dstrow0 + (size_t)nn * ldb + (k0 & ~127) + h * 32 + ((k0 & 64) ? 16 : 0);
  *(uint4*)dst = u.q;
}

// ---------------- weight transpose+convert: WT8[1536][1024] fp8 phys-K ----------------
// WT8[g*512+e][physk(i*512+d)] = Wg[i][d][e]
__global__ __launch_bounds__(256) void wconv(const float* __restrict__ Wz,
                                             const float* __restrict__ Wf,
                                             const float* __restrict__ Wo,
                                             unsigned char* __restrict__ WT8) {
  __shared__ float tile[64][65];
  int z = blockIdx.z, g = z >> 1, i = z & 1;
  const float* src = (g == 0) ? Wz : (g == 1 ? Wf : Wo);
  src += (size_t)i * D * D;
  int d0 = blockIdx.x * 64, e0 = blockIdx.y * 64;
  int t = threadIdx.x, c = t & 63, rq = t >> 6;
#pragma unroll
  for (int p = 0; p < 16; ++p) {
    int dd = p * 4 + rq;
    tile[dd][c] = src[(size_t)(d0 + dd) * D + e0 + c];   // [k=d][n=e]
  }
  __syncthreads();
  tconv_write(tile, WT8 + (size_t)(g * D + e0) * 1024, 1024, i * 512 + d0, t);
}

// ---------------- softmax weight transpose+convert: SW8T[32000][512] fp8 phys-K ----------------
__global__ __launch_bounds__(256) void swconv(const float* __restrict__ SW,
                                              unsigned char* __restrict__ SWT) {
  __shared__ float tile[64][65];
  int k0 = blockIdx.x * 64, n0 = blockIdx.y * 64;
  int t = threadIdx.x, c = t & 63, rq = t >> 6;
#pragma unroll
  for (int p = 0; p < 16; ++p) {
    int kk = p * 4 + rq;
    tile[kk][c] = SW[(size_t)(k0 + kk) * V + n0 + c];
  }
  __syncthreads();
  tconv_write(tile, SWT + (size_t)n0 * 512, 512, k0, t);
}

// ---------------- bias concat ----------------
__global__ void bcat_kernel(const float* bz0, const float* bf0, const float* bo0,
                            const float* bz1, const float* bf1, const float* bo1,
                            float* BC0, float* BC1) {
  int idx = blockIdx.x * 256 + threadIdx.x;
  if (idx >= 2 * G3) return;
  int layer = idx / G3, rem = idx % G3, g = rem >> 9, e = rem & 511;
  const float* s = (layer == 0) ? (g == 0 ? bz0 : (g == 1 ? bf0 : bo0))
                                : (g == 0 ? bz1 : (g == 1 ? bf1 : bo1));
  (layer == 0 ? BC0 : BC1)[rem] = s[e];
}

// ---------------- shared MX-fp8 128x128 GEMM core (verified round 9) ----------------
// 256 thr / 4 waves (wm,wn in 2x2 of 64x64), BK=128, 32KB LDS single-buffered.
// Operands SWAPPED in the MFMA (mfma(b8, a8)): C row = lane&15 (lane-local),
// C col = (lane>>4)*4 + j. Row = 128B = 8 slots of 16B; LDS slot s of row r
// holds source slot s^(r&7) (pre-swizzled global source, rule #21); frag reads
// at slots (hi*2+q)^(r&7).
template<int LD, int NKT>
__device__ __forceinline__ void mx_core(const unsigned char* __restrict__ A,
                                        const unsigned char* __restrict__ B,
                                        int row0, int col0, char* lds,
                                        f32x4 acc[4][4]) {
  char* As = lds;
  char* Bs = lds + 16384;
  const int t = threadIdx.x, lane = t & 63, w = t >> 6;
  const int wm = w >> 1, wn = w & 1;
  const int lo = lane & 15, hi = lane >> 4;
  const int gr = t >> 3;             // row within 32-row issue
  const int ss = (t & 7) ^ (gr & 7); // inverse-swizzled source slot
  const int x  = lo & 7;             // frag-read row swizzle

#pragma unroll 1
  for (int kt = 0; kt < NKT; ++kt) {
    const int k0 = kt * 128;
#pragma unroll
    for (int i = 0; i < 4; ++i) {
      gload16(A + (size_t)(row0 + i * 32 + gr) * LD + k0 + ss * 16,
              As + i * 4096 + t * 16);
      gload16(B + (size_t)(col0 + i * 32 + gr) * LD + k0 + ss * 16,
              Bs + i * 4096 + t * 16);
    }
    __syncthreads();
    i32x8 b8[4];
#pragma unroll
    for (int ni = 0; ni < 4; ++ni) {
      const char* rb = Bs + (wn * 64 + ni * 16 + lo) * 128;
      union { i32x8 v8; i32x4 v4[2]; } u;
      u.v4[0] = *(const i32x4*)(rb + ((hi * 2 + 0) ^ x) * 16);
      u.v4[1] = *(const i32x4*)(rb + ((hi * 2 + 1) ^ x) * 16);
      b8[ni] = u.v8;
    }
#pragma unroll
    for (int mi = 0; mi < 4; ++mi) {
      const char* rb = As + (wm * 64 + mi * 16 + lo) * 128;
      union { i32x8 v8; i32x4 v4[2]; } u;
      u.v4[0] = *(const i32x4*)(rb + ((hi * 2 + 0) ^ x) * 16);
      u.v4[1] = *(const i32x4*)(rb + ((hi * 2 + 1) ^ x) * 16);
      i32x8 a8 = u.v8;
#pragma unroll
      for (int ni = 0; ni < 4; ++ni)
        acc[mi][ni] = __builtin_amdgcn_mfma_scale_f32_16x16x128_f8f6f4(
            b8[ni], a8, acc[mi][ni], 0, 0, 0, 0x7F, 0, 0x7F);
    }
    __syncthreads();
  }
}

// ---------------- QRNN pre-activation GEMM (8192x1536x1024, MX-fp8) ----------------
__global__ __launch_bounds__(256, 2) void gemm_pre_fp8(const unsigned char* __restrict__ A,
                                                       const unsigned char* __restrict__ B,
                                                       const float* __restrict__ bcat,
                                                       ushort* __restrict__ PRE) {
  __shared__ char lds[32768];
  const int t = threadIdx.x, lane = t & 63, w = t >> 6;
  const int wm = w >> 1, wn = w & 1;
  const int lo = lane & 15, hi = lane >> 4;
  const int row0 = blockIdx.x * 128, col0 = blockIdx.y * 128;

  f32x4 acc[4][4];
#pragma unroll
  for (int i = 0; i < 4; ++i)
#pragma unroll
    for (int j = 0; j < 4; ++j) { f32x4 z = {0.f,0.f,0.f,0.f}; acc[i][j] = z; }

  mx_core<1024, 8>(A, B, row0, col0, lds, acc);

  // swapped layout: row = +lo (lane-local), col = colb + j -> ushort4 stores
#pragma unroll
  for (int mi = 0; mi < 4; ++mi) {
    const int row = row0 + wm * 64 + mi * 16 + lo;
#pragma unroll
    for (int ni = 0; ni < 4; ++ni) {
      const int colb = col0 + wn * 64 + ni * 16 + hi * 4;
      ushort4 v;
      v.x = f2bf(acc[mi][ni][0] + bcat[colb + 0]);
      v.y = f2bf(acc[mi][ni][1] + bcat[colb + 1]);
      v.z = f2bf(acc[mi][ni][2] + bcat[colb + 2]);
      v.w = f2bf(acc[mi][ni][3] + bcat[colb + 3]);
      *(ushort4*)(PRE + (size_t)row * G3 + colb) = v;
    }
  }
}

// ---------------- MX-fp8 logits GEMM (8192x32000x512) + fused exp-sum + target ----------------
__global__ __launch_bounds__(256, 2) void gemm_lse_fp8(const unsigned char* __restrict__ A,
                                                       const unsigned char* __restrict__ B,
                                                       const float* __restrict__ SB,
                                                       const int* __restrict__ tgt,
                                                       float* __restrict__ SUM,
                                                       float* __restrict__ TGL) {
  __shared__ char lds[32768];
  const int t = threadIdx.x, lane = t & 63, w = t >> 6;
  const int wm = w >> 1, wn = w & 1;
  const int lo = lane & 15, hi = lane >> 4;
  const int row0 = blockIdx.x * 128, col0 = blockIdx.y * 128;

  f32x4 acc[4][4];
#pragma unroll
  for (int i = 0; i < 4; ++i)
#pragma unroll
    for (int j = 0; j < 4; ++j) { f32x4 z = {0.f,0.f,0.f,0.f}; acc[i][j] = z; }

  mx_core<512, 4>(A, B, row0, col0, lds, acc);

  // epilogue (swapped layout): out_row = row0+wm*64+mi*16+lo (lane-local!),
  // vocab_col = col0+wn*64+ni*16+hi*4+j. In-lane exp-sum over (ni,j);
  // 2-stage shfl over hi lanes; one atomic per row per wave.
#pragma unroll
  for (int mi = 0; mi < 4; ++mi) {
    const int row = row0 + wm * 64 + mi * 16 + lo;
    const int tg  = tgt[row];
    float s = 0.f;
#pragma unroll
    for (int ni = 0; ni < 4; ++ni) {
      const int colb = col0 + wn * 64 + ni * 16 + hi * 4;
#pragma unroll
      for (int j = 0; j < 4; ++j) {
        float v = acc[mi][ni][j] + SB[colb + j];
        if (colb + j == tg) TGL[row] = v;    // exactly one writer per row
        s += __expf(v);
      }
    }
    s += __shfl_xor(s, 16, 64);
    s += __shfl_xor(s, 32, 64);
    if (hi == 0) atomicAdd(&SUM[row], s);
  }
}

// ---------------- fo-pool scan (bf16 in; fp8 phys-K out) ----------------
// mode 0: OUT8 = YA8 [R][1024]: [r][512+pk]=h, [r+1][pk]=h (t<255), [r][pk]=0 (t==0)
// mode 1: OUT8 = H8 [R][512]
__global__ __launch_bounds__(64) void scan_kernel(const ushort* __restrict__ PRE,
                                                  unsigned char* __restrict__ OUT8,
                                                  int mode) {
  int idx = blockIdx.x * 64 + threadIdx.x;    // 32*512
  int b = idx >> 9, d = idx & 511;
  const ushort* p = PRE + (size_t)b * TT * G3 + d;
  int poff = physk(d);
  float c = 0.f;
  for (int t0 = 0; t0 < TT; t0 += 8) {
    float pz[8], pf[8], po[8];
#pragma unroll
    for (int i = 0; i < 8; ++i) {
      const ushort* q = p + (size_t)(t0 + i) * G3;
      pz[i] = bf2f(q[0]); pf[i] = bf2f(q[512]); po[i] = bf2f(q[1024]);
    }
#pragma unroll
    for (int i = 0; i < 8; ++i) {
      float z = 2.f / (1.f + __expf(-2.f * pz[i])) - 1.f;
      float f = 1.f / (1.f + __expf(-pf[i]));
      float o = 1.f / (1.f + __expf(-po[i]));
      c = f * c + (1.f - f) * z;
      float h = o * c;
      int tt = t0 + i;
      size_t r = (size_t)b * TT + tt;
      unsigned char hb = f2e4m3(h);
      if (mode == 0) {
        OUT8[r * 1024 + 512 + poff] = hb;
        if (tt < TT - 1) OUT8[(r + 1) * 1024 + poff] = hb;
        if (tt == 0)     OUT8[r * 1024 + poff] = 0;
      } else {
        OUT8[r * 512 + poff] = hb;
      }
    }
  }
}

// ---------------- helpers ----------------
__global__ void zero_kernel(float* __restrict__ p, int n) {
  int i = blockIdx.x * 256 + threadIdx.x;
  if (i < n) p[i] = 0.f;
}

__global__ __launch_bounds__(256) void cost_kernel(const float* __restrict__ sumexp,
                                                   const float* __restrict__ tgl,
                                                   float* __restrict__ out) {
  int t = threadIdx.x;
  float s = 0.f;
  for (int r = t; r < R; r += 256) s += logf(sumexp[r]) - tgl[r];
#pragma unroll
  for (int m = 1; m < 64; m <<= 1) s += __shfl_xor(s, m, 64);
  __shared__ float red[4];
  int wave = t >> 6, lane = t & 63;
  if (lane == 0) red[wave] = s;
  __syncthreads();
  if (t == 0) out[0] = (red[0] + red[1] + red[2] + red[3]) / (float)R;
}

extern "C" void kernel_launch(void* const* d_in, const int* in_sizes, int n_in,
                              void* d_out, int out_size, void* d_ws, size_t ws_size,
                              hipStream_t stream) {
  const int*   tok = (const int*)d_in[0];
  const int*   tgt = (const int*)d_in[1];
  const float* emb = (const float*)d_in[2];
  const float* Wz0 = (const float*)d_in[3];  const float* bz0 = (const float*)d_in[4];
  const float* Wf0 = (const float*)d_in[5];  const float* bf0 = (const float*)d_in[6];
  const float* Wo0 = (const float*)d_in[7];  const float* bo0 = (const float*)d_in[8];
  const float* Wz1 = (const float*)d_in[9];  const float* bz1 = (const float*)d_in[10];
  const float* Wf1 = (const float*)d_in[11]; const float* bf1 = (const float*)d_in[12];
  const float* Wo1 = (const float*)d_in[13]; const float* bo1 = (const float*)d_in[14];
  const float* SW  = (const float*)d_in[15]; const float* SB  = (const float*)d_in[16];
  float* out = (float*)d_out;

  // workspace layout (bytes), total ~49.4 MB:
  char* base = (char*)d_ws;
  unsigned char* XA8 = (unsigned char*)(base);             //  8,388,608 [R][1024] fp8 phys-K
  unsigned char* YA8 = (unsigned char*)(base + 8388608);   //  8,388,608 [R][1024] fp8 phys-K
  ushort*        PRE = (ushort*)(base + 16777216);         // 25,165,824 [R][1536] bf16
  unsigned char* H8  = (unsigned char*)(base + 41943040);  //  4,194,304 [R][512]  fp8 phys-K
  unsigned char* WT80 = (unsigned char*)(base + 46137344); //  1,572,864 [1536][1024] fp8 phys-K
  unsigned char* WT81 = (unsigned char*)(base + 47710208); //  1,572,864
  float*         BC0 = (float*)(base + 49283072);          //  6,144
  float*         BC1 = (float*)(base + 49289216);          //  6,144
  float*         SUM = (float*)(base + 49295360);          //  32,768
  float*         TGL = (float*)(base + 49328128);          //  32,768
  unsigned char* SW8T = (unsigned char*)(base);            // 16,384,000 — aliases XA8+YA8 (dead by then)

  embed_kernel<<<R * 128 / 256, 256, 0, stream>>>(tok, (const float4*)emb, XA8);
  wconv<<<dim3(8, 8, 6), 256, 0, stream>>>(Wz0, Wf0, Wo0, WT80);
  wconv<<<dim3(8, 8, 6), 256, 0, stream>>>(Wz1, Wf1, Wo1, WT81);
  bcat_kernel<<<12, 256, 0, stream>>>(bz0, bf0, bo0, bz1, bf1, bo1, BC0, BC1);

  gemm_pre_fp8<<<dim3(64, 12), 256, 0, stream>>>(XA8, WT80, BC0, PRE);
  scan_kernel<<<256, 64, 0, stream>>>(PRE, YA8, 0);
  gemm_pre_fp8<<<dim3(64, 12), 256, 0, stream>>>(YA8, WT81, BC1, PRE);
  scan_kernel<<<256, 64, 0, stream>>>(PRE, H8, 1);

  // SW8T aliases XA8/YA8 — both dead after the second gemm_pre_fp8
  swconv<<<dim3(8, 500), 256, 0, stream>>>(SW, SW8T);
  zero_kernel<<<32, 256, 0, stream>>>(SUM, R);
  gemm_lse_fp8<<<dim3(64, 250), 256, 0, stream>>>(H8, SW8T, SB, tgt, SUM, TGL);
  cost_kernel<<<1, 256, 0, stream>>>(SUM, TGL, out);
}